// Round 6
// baseline (693.222 us; speedup 1.0000x reference)
//
#include <hip/hip_runtime.h>

// GATv2 stack on MI355X. fp32 throughout (no fp32 MFMA on CDNA4 -> vector ALU).
// R21: split the fused gat+proj kernel. Six structural variants (R15-R20) all
// landed at ~46us with no saturated pipe (VALU 40-54%, HBM 15%, L2 ~8%) ->
// fused phases alias each other in the counters; attribution impossible.
// Split: k_gat2e = edge/attention only (writes o to hbuf); k_projdual =
// blocked LDS-GEMM dual projection (k_proj64 pattern, same FLOPs as the old
// shuffle epilogue but GEMM-efficient: no 64 shfl/node, no 128 global weight
// loads/wave); k_projpk = packed final projection. Costs +12.8MB/layer
// streaming traffic (~2-3us); buys per-phase rocprof rows + GEMM-rate proj.

static __device__ __forceinline__ float lrelu(float x, float s) {
    return fmaxf(x, s * x);  // exact for 0<s<1
}

// ---------------- degree + rank ----------------
__global__ void k_build0(const int* __restrict__ dst, int* __restrict__ cnt,
                         int* __restrict__ rank, int E) {
    int idx = blockIdx.x * blockDim.x + threadIdx.x;
    if (idx < E) rank[idx] = atomicAdd(&cnt[dst[idx]], 1);
}

// wave-aggregated segment offset allocation (exactly cnt[i] slots per node)
__global__ void k_segoff(const int* __restrict__ cnt, int* __restrict__ row_start,
                         int* __restrict__ cursor, int n) {
    int i = blockIdx.x * blockDim.x + threadIdx.x;
    int lane = threadIdx.x & 63;
    int v = (i < n) ? cnt[i] : 0;
    int s = v;
#pragma unroll
    for (int off = 1; off < 64; off <<= 1) {
        int t = __shfl_up(s, off);
        if (lane >= off) s += t;
    }
    int wavetot = __shfl(s, 63);
    int base = 0;
    if (lane == 63) base = atomicAdd(cursor, wavetot);
    base = __shfl(base, 63);
    if (i < n) row_start[i] = base + s - v;
}

__global__ void k_scatter(const int* __restrict__ src, const int* __restrict__ dst,
                          const float* __restrict__ ea, const int* __restrict__ rank,
                          const int* __restrict__ row_start,
                          int* __restrict__ csr_src, float* __restrict__ csr_ea, int E) {
    int e = blockIdx.x * blockDim.x + threadIdx.x;
    if (e >= E) return;
    int pos = row_start[dst[e]] + rank[e];
    csr_src[pos] = src[e];
    *(float2*)(csr_ea + 2 * (size_t)pos) = *(const float2*)(ea + 2 * (size_t)e);
}

// ---------------- layer-0 gat: on-the-fly rank-2 projection ----------------
__launch_bounds__(256, 8)
__global__ void k_gat0(const float* __restrict__ x,
                       const int* __restrict__ row_start, const int* __restrict__ cnt,
                       const int* __restrict__ csr_src, const float* __restrict__ csr_ea,
                       const float* __restrict__ Wl, const float* __restrict__ bl,
                       const float* __restrict__ Wr, const float* __restrict__ br,
                       const float* __restrict__ We, const float* __restrict__ att,
                       const float* __restrict__ bias,
                       float* __restrict__ out, int n) {
    int d = (blockIdx.x * blockDim.x + threadIdx.x) >> 6;
    int lane = threadIdx.x & 63;
    if (d >= n) return;
    const int p0 = __builtin_amdgcn_readfirstlane(row_start[d]);
    const int deg = __builtin_amdgcn_readfirstlane(cnt[d]);
    const int p1 = p0 + deg;
    const float wl0 = Wl[lane], wl1 = Wl[64 + lane], blv = bl[lane];
    const float we0 = We[lane], we1 = We[64 + lane];
    const float av = att[lane];
    const float2 xd = *(const float2*)(x + 2 * (size_t)d);
    const float xrv = fmaf(xd.x, Wr[lane], fmaf(xd.y, Wr[64 + lane], br[lane]));

    float den0 = 0.f, acc0 = 0.f;
    float den1 = 0.f, acc1 = 0.f;
    float s0 = 0.f, s1 = 0.f;

    auto step = [&](float xv, float2 ea, bool valid, float& den, float& acc) {
        float vm = valid ? 1.f : 0.f;
        s0 = fmaf(vm, ea.x, s0);
        s1 = fmaf(vm, ea.y, s1);
        float tv = lrelu(xv + xrv + ea.x * we0 + ea.y * we1, 0.2f) * av;
        tv += __shfl_xor(tv, 1);
        tv += __shfl_xor(tv, 2);
        if (!valid) tv = -__builtin_inff();
        float w = __expf(tv);
        den += w;
        acc += w * xv;
    };

    for (int p = p0; p < p1; p += 4) {
        int q1 = min(p + 1, p1 - 1), q2 = min(p + 2, p1 - 1), q3 = min(p + 3, p1 - 1);
        int e0s = csr_src[p], e1s = csr_src[q1], e2s = csr_src[q2], e3s = csr_src[q3];
        float2 ea0 = *(const float2*)(csr_ea + 2 * (size_t)p);
        float2 ea1 = *(const float2*)(csr_ea + 2 * (size_t)q1);
        float2 ea2 = *(const float2*)(csr_ea + 2 * (size_t)q2);
        float2 ea3 = *(const float2*)(csr_ea + 2 * (size_t)q3);
        float2 xs0 = *(const float2*)(x + 2 * (size_t)e0s);
        float2 xs1 = *(const float2*)(x + 2 * (size_t)e1s);
        float2 xs2 = *(const float2*)(x + 2 * (size_t)e2s);
        float2 xs3 = *(const float2*)(x + 2 * (size_t)e3s);
        float xv0 = fmaf(xs0.x, wl0, fmaf(xs0.y, wl1, blv));
        float xv1 = fmaf(xs1.x, wl0, fmaf(xs1.y, wl1, blv));
        float xv2 = fmaf(xs2.x, wl0, fmaf(xs2.y, wl1, blv));
        float xv3 = fmaf(xs3.x, wl0, fmaf(xs3.y, wl1, blv));
        step(xv0, ea0, true, den0, acc0);
        step(xv1, ea1, p + 1 < p1, den1, acc1);
        step(xv2, ea2, p + 2 < p1, den0, acc0);
        step(xv3, ea3, p + 3 < p1, den1, acc1);
    }
    {
        float c = fmaxf((float)deg, 1.f);
        float se0 = s0 / c, se1 = s1 / c;
        float xv = fmaf(xd.x, wl0, fmaf(xd.y, wl1, blv));
        float tv = lrelu(xv + xrv + se0 * we0 + se1 * we1, 0.2f) * av;
        tv += __shfl_xor(tv, 1);
        tv += __shfl_xor(tv, 2);
        float w = __expf(tv);
        den0 += w;
        acc0 += w * xv;
    }
    out[((size_t)d << 6) + lane] = (acc0 + acc1) / (den0 + den1) + bias[lane];
}

// ---------------- layer-0 projection with fused BN (reads hbuf) ----------------
__launch_bounds__(256)
__global__ void k_proj64(const float* __restrict__ h,
                         const float* __restrict__ Wl, const float* __restrict__ bl,
                         const float* __restrict__ Wr, const float* __restrict__ br,
                         const double* __restrict__ stats,
                         const float* __restrict__ bng, const float* __restrict__ bnb,
                         float* __restrict__ xl, float* __restrict__ xr, int n) {
    __shared__ float wsl[4096], wsr[4096], bna[64], bnbb[64];
    int t = threadIdx.x;
    for (int i = t; i < 4096; i += 256) { wsl[i] = Wl[i]; wsr[i] = Wr[i]; }
    if (t < 64) {
        double mu = stats[t] / n;
        double var = stats[64 + t] / n - mu * mu;
        float rs = (float)(1.0 / sqrt(var + 1e-5));
        float a = rs * bng[t];
        bna[t] = a;
        bnbb[t] = bnb[t] - (float)mu * a;
    }
    __syncthreads();
    int rg = t >> 2, cg4 = (t & 3) << 4;
    int r0 = blockIdx.x * 128 + rg * 2;
    float accl[2][16], accr[2][16];
#pragma unroll
    for (int r = 0; r < 2; ++r)
#pragma unroll
        for (int j = 0; j < 16; ++j) { accl[r][j] = 0.f; accr[r][j] = 0.f; }
    for (int k0 = 0; k0 < 64; k0 += 4) {
        float hk[2][4];
#pragma unroll
        for (int r = 0; r < 2; ++r) {
            int gr = r0 + r;
            float4 v = (gr < n) ? *(const float4*)(h + (size_t)gr * 64 + k0)
                                : make_float4(0.f, 0.f, 0.f, 0.f);
            hk[r][0] = v.x; hk[r][1] = v.y; hk[r][2] = v.z; hk[r][3] = v.w;
#pragma unroll
            for (int kk = 0; kk < 4; ++kk)
                hk[r][kk] = lrelu(hk[r][kk] * bna[k0 + kk] + bnbb[k0 + kk], 0.01f);
        }
#pragma unroll
        for (int kk = 0; kk < 4; ++kk) {
            const float* wl = wsl + (k0 + kk) * 64 + cg4;
            const float* wr = wsr + (k0 + kk) * 64 + cg4;
#pragma unroll
            for (int r = 0; r < 2; ++r)
#pragma unroll
                for (int j = 0; j < 16; ++j) {
                    accl[r][j] += hk[r][kk] * wl[j];
                    accr[r][j] += hk[r][kk] * wr[j];
                }
        }
    }
#pragma unroll
    for (int r = 0; r < 2; ++r) {
        int gr = r0 + r;
        if (gr < n) {
            float* ol = xl + (size_t)gr * 64 + cg4;
            float* orr = xr + (size_t)gr * 64 + cg4;
#pragma unroll
            for (int j = 0; j < 16; ++j) {
                ol[j] = accl[r][j] + bl[cg4 + j];
                orr[j] = accr[r][j] + br[cg4 + j];
            }
        }
    }
}

// ---------------- gat node body (R15-proven) ----------------
__device__ __forceinline__ float gat_node(const float* __restrict__ xl,
                                          const float* __restrict__ xr,
                                          const int* __restrict__ row_start,
                                          const int* __restrict__ cnt,
                                          const int* __restrict__ csr_src,
                                          const float* __restrict__ csr_ea,
                                          const float* __restrict__ We,
                                          const float* __restrict__ att,
                                          const float* __restrict__ bias,
                                          int d, int lane, int relu) {
    const int p0 = __builtin_amdgcn_readfirstlane(row_start[d]);
    const int deg = __builtin_amdgcn_readfirstlane(cnt[d]);
    const int p1 = p0 + deg;
    const float we0 = We[lane], we1 = We[64 + lane];
    const float av = att[lane];
    const float xrv = xr[((size_t)d << 6) + lane];

    float den0 = 0.f, acc0 = 0.f;
    float den1 = 0.f, acc1 = 0.f;
    float s0 = 0.f, s1 = 0.f;  // masked ea sums for the self-loop attr

    auto step = [&](float xv, float2 ea, bool valid, float& den, float& acc) {
        float vm = valid ? 1.f : 0.f;
        s0 = fmaf(vm, ea.x, s0);
        s1 = fmaf(vm, ea.y, s1);
        float tv = lrelu(xv + xrv + ea.x * we0 + ea.y * we1, 0.2f) * av;
        tv += __shfl_xor(tv, 1);
        tv += __shfl_xor(tv, 2);
        if (!valid) tv = -__builtin_inff();
        float w = __expf(tv);
        den += w;
        acc += w * xv;
    };

    for (int p = p0; p < p1; p += 4) {
        int q1 = min(p + 1, p1 - 1), q2 = min(p + 2, p1 - 1), q3 = min(p + 3, p1 - 1);
        int e0s = csr_src[p], e1s = csr_src[q1], e2s = csr_src[q2], e3s = csr_src[q3];
        float2 e0 = *(const float2*)(csr_ea + 2 * (size_t)p);
        float2 e1 = *(const float2*)(csr_ea + 2 * (size_t)q1);
        float2 e2 = *(const float2*)(csr_ea + 2 * (size_t)q2);
        float2 e3 = *(const float2*)(csr_ea + 2 * (size_t)q3);
        float x0 = xl[((size_t)e0s << 6) + lane];
        float x1 = xl[((size_t)e1s << 6) + lane];
        float x2 = xl[((size_t)e2s << 6) + lane];
        float x3 = xl[((size_t)e3s << 6) + lane];
        step(x0, e0, true, den0, acc0);
        step(x1, e1, p + 1 < p1, den1, acc1);
        step(x2, e2, p + 2 < p1, den0, acc0);
        step(x3, e3, p + 3 < p1, den1, acc1);
    }
    // self-loop: attr = segment mean, xv = own features
    {
        float c = fmaxf((float)deg, 1.f);
        float se0 = s0 / c, se1 = s1 / c;
        float xv = xl[((size_t)d << 6) + lane];
        float tv = lrelu(xv + xrv + se0 * we0 + se1 * we1, 0.2f) * av;
        tv += __shfl_xor(tv, 1);
        tv += __shfl_xor(tv, 2);
        float w = __expf(tv);
        den0 += w;
        acc0 += w * xv;
    }
    float o = (acc0 + acc1) / (den0 + den1) + bias[lane];
    if (relu) o = lrelu(o, 0.01f);
    return o;
}

// edge/attention-only kernel: 2 nodes per wave, writes relu'd o to hbuf
__launch_bounds__(256, 8)
__global__ void k_gat2e(const float* __restrict__ xl, const float* __restrict__ xr,
                        const int* __restrict__ row_start, const int* __restrict__ cnt,
                        const int* __restrict__ csr_src, const float* __restrict__ csr_ea,
                        const float* __restrict__ We, const float* __restrict__ att,
                        const float* __restrict__ bias,
                        float* __restrict__ out, int n) {
    int wave = (blockIdx.x * blockDim.x + threadIdx.x) >> 6;
    int lane = threadIdx.x & 63;
    int d0 = wave * 2;
    if (d0 >= n) return;
    float o0 = gat_node(xl, xr, row_start, cnt, csr_src, csr_ea, We, att, bias, d0, lane, 1);
    out[((size_t)d0 << 6) + lane] = o0;
    int d1 = d0 + 1;
    if (d1 < n) {
        float o1 = gat_node(xl, xr, row_start, cnt, csr_src, csr_ea, We, att, bias, d1, lane, 1);
        out[((size_t)d1 << 6) + lane] = o1;
    }
}

// dedicated dual projection: blocked LDS-GEMM (k_proj64 minus BN)
__launch_bounds__(256)
__global__ void k_projdual(const float* __restrict__ h,
                           const float* __restrict__ Wl, const float* __restrict__ bl,
                           const float* __restrict__ Wr, const float* __restrict__ br,
                           float* __restrict__ xl, float* __restrict__ xr, int n) {
    __shared__ float wsl[4096], wsr[4096];
    int t = threadIdx.x;
    for (int i = t; i < 4096; i += 256) { wsl[i] = Wl[i]; wsr[i] = Wr[i]; }
    __syncthreads();
    int rg = t >> 2, cg4 = (t & 3) << 4;
    int r0 = blockIdx.x * 128 + rg * 2;
    float accl[2][16], accr[2][16];
#pragma unroll
    for (int r = 0; r < 2; ++r)
#pragma unroll
        for (int j = 0; j < 16; ++j) { accl[r][j] = 0.f; accr[r][j] = 0.f; }
    for (int k0 = 0; k0 < 64; k0 += 4) {
        float hk[2][4];
#pragma unroll
        for (int r = 0; r < 2; ++r) {
            int gr = r0 + r;
            float4 v = (gr < n) ? *(const float4*)(h + (size_t)gr * 64 + k0)
                                : make_float4(0.f, 0.f, 0.f, 0.f);
            hk[r][0] = v.x; hk[r][1] = v.y; hk[r][2] = v.z; hk[r][3] = v.w;
        }
#pragma unroll
        for (int kk = 0; kk < 4; ++kk) {
            const float* wl = wsl + (k0 + kk) * 64 + cg4;
            const float* wr = wsr + (k0 + kk) * 64 + cg4;
#pragma unroll
            for (int r = 0; r < 2; ++r)
#pragma unroll
                for (int j = 0; j < 16; ++j) {
                    accl[r][j] += hk[r][kk] * wl[j];
                    accr[r][j] += hk[r][kk] * wr[j];
                }
        }
    }
#pragma unroll
    for (int r = 0; r < 2; ++r) {
        int gr = r0 + r;
        if (gr < n) {
            float* ol = xl + (size_t)gr * 64 + cg4;
            float* orr = xr + (size_t)gr * 64 + cg4;
#pragma unroll
            for (int j = 0; j < 16; ++j) {
                ol[j] = accl[r][j] + bl[cg4 + j];
                orr[j] = accr[r][j] + br[cg4 + j];
            }
        }
    }
}

// packed final projection: packed[d] = [f_xl(16) | s_xl(16) | f_xr(16) | s_xr(16)]
__launch_bounds__(256)
__global__ void k_projpk(const float* __restrict__ h,
                         const float* __restrict__ fWl, const float* __restrict__ fbl,
                         const float* __restrict__ sWl, const float* __restrict__ sbl,
                         const float* __restrict__ fWr, const float* __restrict__ fbr,
                         const float* __restrict__ sWr, const float* __restrict__ sbr,
                         float* __restrict__ packed, int n) {
    __shared__ float ws[4096], bs[64];
    int t = threadIdx.x;
    for (int i = t; i < 4096; i += 256) {
        int k = i >> 6, c = i & 63, q = c >> 4, cc = c & 15;
        const float* W = (q == 0) ? fWl : (q == 1) ? sWl : (q == 2) ? fWr : sWr;
        ws[i] = W[k * 16 + cc];
    }
    if (t < 64) {
        int q = t >> 4, cc = t & 15;
        const float* B = (q == 0) ? fbl : (q == 1) ? sbl : (q == 2) ? fbr : sbr;
        bs[t] = B[cc];
    }
    __syncthreads();
    int rg = t >> 2, cg4 = (t & 3) << 4;
    int r0 = blockIdx.x * 128 + rg * 2;
    float acc[2][16];
#pragma unroll
    for (int r = 0; r < 2; ++r)
#pragma unroll
        for (int j = 0; j < 16; ++j) acc[r][j] = 0.f;
    for (int k0 = 0; k0 < 64; k0 += 4) {
        float hk[2][4];
#pragma unroll
        for (int r = 0; r < 2; ++r) {
            int gr = r0 + r;
            float4 v = (gr < n) ? *(const float4*)(h + (size_t)gr * 64 + k0)
                                : make_float4(0.f, 0.f, 0.f, 0.f);
            hk[r][0] = v.x; hk[r][1] = v.y; hk[r][2] = v.z; hk[r][3] = v.w;
        }
#pragma unroll
        for (int kk = 0; kk < 4; ++kk) {
            const float* w = ws + (k0 + kk) * 64 + cg4;
#pragma unroll
            for (int r = 0; r < 2; ++r)
#pragma unroll
                for (int j = 0; j < 16; ++j) acc[r][j] += hk[r][kk] * w[j];
        }
    }
#pragma unroll
    for (int r = 0; r < 2; ++r) {
        int gr = r0 + r;
        if (gr < n) {
            float* op = packed + (size_t)gr * 64 + cg4;
#pragma unroll
            for (int j = 0; j < 16; ++j) op[j] = acc[r][j] + bs[cg4 + j];
        }
    }
}

// final two H=16,C=1 layers fused: half-wave per dst (0-15 f -> fin, 16-31 s -> mus)
__launch_bounds__(256)
__global__ void k_gat_final(const float* __restrict__ packed,
                            const int* __restrict__ row_start, const int* __restrict__ cnt,
                            const int* __restrict__ csr_src, const float* __restrict__ csr_ea,
                            const float* __restrict__ fWe, const float* __restrict__ sWe,
                            const float* __restrict__ fatt, const float* __restrict__ satt,
                            const float* __restrict__ fbias, const float* __restrict__ sbias,
                            float* __restrict__ fin, float* __restrict__ mus, int n) {
    int hw = (blockIdx.x * blockDim.x + threadIdx.x) >> 5;
    if (hw >= n) return;
    int l = threadIdx.x & 31;
    int hh = l & 15, sel = l >> 4;
    const int d = hw;
    const int p0 = row_start[d], deg = cnt[d], p1 = p0 + deg;
    const float* We = sel ? sWe : fWe;
    float we0 = We[hh], we1 = We[16 + hh];
    float av = (sel ? satt : fatt)[hh];
    float xrv = packed[(size_t)d * 64 + 32 + sel * 16 + hh];
    int xli = sel * 16 + hh;

    float den0 = 0.f, acc0 = 0.f;
    float den1 = 0.f, acc1 = 0.f;
    float s0 = 0.f, s1 = 0.f;

    auto step = [&](float xv, float2 ea, bool valid, float& den, float& acc) {
        float vm = valid ? 1.f : 0.f;
        s0 = fmaf(vm, ea.x, s0);
        s1 = fmaf(vm, ea.y, s1);
        float t = lrelu(xv + xrv + ea.x * we0 + ea.y * we1, 0.2f) * av;
        if (!valid) t = -__builtin_inff();
        float w = __expf(t);
        den += w;
        acc += w * xv;
    };

    for (int p = p0; p < p1; p += 4) {
        int q1 = min(p + 1, p1 - 1), q2 = min(p + 2, p1 - 1), q3 = min(p + 3, p1 - 1);
        int e0s = csr_src[p], e1s = csr_src[q1], e2s = csr_src[q2], e3s = csr_src[q3];
        float2 e0 = *(const float2*)(csr_ea + 2 * (size_t)p);
        float2 e1 = *(const float2*)(csr_ea + 2 * (size_t)q1);
        float2 e2 = *(const float2*)(csr_ea + 2 * (size_t)q2);
        float2 e3 = *(const float2*)(csr_ea + 2 * (size_t)q3);
        float x0 = packed[(size_t)e0s * 64 + xli];
        float x1 = packed[(size_t)e1s * 64 + xli];
        float x2 = packed[(size_t)e2s * 64 + xli];
        float x3 = packed[(size_t)e3s * 64 + xli];
        step(x0, e0, true, den0, acc0);
        step(x1, e1, p + 1 < p1, den1, acc1);
        step(x2, e2, p + 2 < p1, den0, acc0);
        step(x3, e3, p + 3 < p1, den1, acc1);
    }
    {
        float c = fmaxf((float)deg, 1.f);
        float se0 = s0 / c, se1 = s1 / c;
        float xv = packed[(size_t)d * 64 + xli];
        float t = lrelu(xv + xrv + se0 * we0 + se1 * we1, 0.2f) * av;
        float w = __expf(t);
        den0 += w;
        acc0 += w * xv;
    }
    float val = (acc0 + acc1) / (den0 + den1);
#pragma unroll
    for (int w = 1; w < 16; w <<= 1) val += __shfl_xor(val, w);
    if ((threadIdx.x & 15) == 0) {
        float o = val * (1.f / 16.f) + (sel ? sbias[0] : fbias[0]);
        if (sel) mus[d] = o; else fin[d] = o;
    }
}

// ---------------- batchnorm stats ----------------

__global__ void k_bnstats(const float* __restrict__ h, double* __restrict__ stats, int n) {
    int c = threadIdx.x & 63;
    int s0 = blockIdx.x * (blockDim.x >> 6) + (threadIdx.x >> 6);
    int ns = gridDim.x * (blockDim.x >> 6);
    double s = 0.0, s2 = 0.0;
    for (int i = s0; i < n; i += ns) {
        float v = h[(size_t)i * 64 + c];
        s += v;
        s2 += (double)v * v;
    }
    atomicAdd(&stats[c], s);
    atomicAdd(&stats[64 + c], s2);
}

// ---------------- graph-level mean over masked nodes ----------------

__global__ void k_sat_acc(const float* __restrict__ fin, const int* __restrict__ mask,
                          const int* __restrict__ batch,
                          float* __restrict__ sums, float* __restrict__ cnts, int n) {
    int i = blockIdx.x * blockDim.x + threadIdx.x;
    int lane = threadIdx.x & 63;
    int g = (i < n) ? batch[i] : -1;
    float c = (i < n && mask[i] == 0) ? 1.f : 0.f;
    float v = (c > 0.f) ? fin[i] : 0.f;
#pragma unroll
    for (int off = 1; off < 64; off <<= 1) {
        float v2 = __shfl_down(v, off);
        float c2 = __shfl_down(c, off);
        int g2 = __shfl_down(g, off);
        if (lane + off < 64 && g2 == g) { v += v2; c += c2; }
    }
    int gprev = __shfl_up(g, 1);
    bool head = (lane == 0) || (gprev != g);
    if (head && g >= 0 && c > 0.f) {
        atomicAdd(&sums[g], v);
        atomicAdd(&cnts[g], c);
    }
}

__global__ void k_sat_fin(const float* __restrict__ sums, const float* __restrict__ cnts,
                          float* __restrict__ out, int g) {
    int i = threadIdx.x;
    if (i < g) out[i] = sums[i] / fmaxf(cnts[i], 1.f);
}

// ---------------- host ----------------

extern "C" void kernel_launch(void* const* d_in, const int* in_sizes, int n_in,
                              void* d_out, int out_size, void* d_ws, size_t ws_size,
                              hipStream_t stream) {
    const float* x = (const float*)d_in[0];
    const float* eat = (const float*)d_in[1];
    const int* ei = (const int*)d_in[2];
    const int* mask = (const int*)d_in[3];
    const int* batch = (const int*)d_in[4];
    const float* g0_Wl = (const float*)d_in[5];
    const float* g0_bl = (const float*)d_in[6];
    const float* g0_Wr = (const float*)d_in[7];
    const float* g0_br = (const float*)d_in[8];
    const float* g0_We = (const float*)d_in[9];
    const float* g0_att = (const float*)d_in[10];
    const float* g0_bias = (const float*)d_in[11];
    const float* bn_g = (const float*)d_in[12];
    const float* bn_b = (const float*)d_in[13];
    const float* m_Wl = (const float*)d_in[14];
    const float* m_bl = (const float*)d_in[15];
    const float* m_Wr = (const float*)d_in[16];
    const float* m_br = (const float*)d_in[17];
    const float* m_We = (const float*)d_in[18];
    const float* m_att = (const float*)d_in[19];
    const float* m_bias = (const float*)d_in[20];
    const float* f_Wl = (const float*)d_in[21];
    const float* f_bl = (const float*)d_in[22];
    const float* f_Wr = (const float*)d_in[23];
    const float* f_br = (const float*)d_in[24];
    const float* f_We = (const float*)d_in[25];
    const float* f_att = (const float*)d_in[26];
    const float* f_bias = (const float*)d_in[27];
    const float* s_Wl = (const float*)d_in[28];
    const float* s_bl = (const float*)d_in[29];
    const float* s_Wr = (const float*)d_in[30];
    const float* s_br = (const float*)d_in[31];
    const float* s_We = (const float*)d_in[32];
    const float* s_att = (const float*)d_in[33];
    const float* s_bias = (const float*)d_in[34];

    const int N = in_sizes[3];
    const int E = in_sizes[1] / 2;
    const int G = out_size - N;
    const int ITER = in_sizes[14] / 4096;
    const int* srcp = ei;
    const int* dstp = ei + E;

    char* wsb = (char*)d_ws;
    size_t off = 0;
    auto alloc = [&](size_t b) { void* p = wsb + off; off = (off + b + 255) & ~(size_t)255; return p; };
    int* cnt = (int*)alloc((size_t)N * 4);
    int* cursor = (int*)alloc(256);
    double* stats = (double*)alloc(128 * 8);
    float* sums = (float*)alloc((size_t)G * 4);
    float* cnts = (float*)alloc((size_t)G * 4);
    size_t zero_bytes = off;
    int* rank = (int*)alloc((size_t)E * 4);
    int* row_start = (int*)alloc((size_t)N * 4);
    int* csr_src = (int*)alloc((size_t)(E + 4) * 4);
    float* csr_ea = (float*)alloc((size_t)(E + 4) * 8);
    float* xlA = (float*)alloc((size_t)N * 256);
    float* xrA = (float*)alloc((size_t)N * 256);
    float* xlB = (float*)alloc((size_t)N * 256);
    float* xrB = (float*)alloc((size_t)N * 256);
    float* hbuf = (float*)alloc((size_t)N * 256);
    float* fin = (float*)alloc((size_t)N * 4);
    (void)ws_size; (void)n_in;

    float* outv = (float*)d_out;  // [0,N) = mus, [N,N+G) = sat

    hipMemsetAsync(d_ws, 0, zero_bytes, stream);
    const int tb = 256;
    const int ggrid = (N * 64 + 255) / 256;
    const int npair = (N + 1) / 2;
    const int ggrid2 = (npair * 64 + 255) / 256;
    const int pgrid = (N + 127) / 128;
    k_build0<<<(E + tb - 1) / tb, tb, 0, stream>>>(dstp, cnt, rank, E);
    k_segoff<<<(N + tb - 1) / tb, tb, 0, stream>>>(cnt, row_start, cursor, N);
    k_scatter<<<(E + tb - 1) / tb, tb, 0, stream>>>(srcp, dstp, eat, rank, row_start,
                                                    csr_src, csr_ea, E);

    k_gat0<<<ggrid, tb, 0, stream>>>(x, row_start, cnt, csr_src, csr_ea,
                                     g0_Wl, g0_bl, g0_Wr, g0_br,
                                     g0_We, g0_att, g0_bias, hbuf, N);
    k_bnstats<<<128, 256, 0, stream>>>(hbuf, stats, N);
    k_proj64<<<pgrid, 256, 0, stream>>>(hbuf, m_Wl, m_bl, m_Wr, m_br,
                                        stats, bn_g, bn_b, xlA, xrA, N);

    float* cur_l = xlA; float* cur_r = xrA;
    float* alt_l = xlB; float* alt_r = xrB;
    for (int l = 0; l < ITER; ++l) {
        k_gat2e<<<ggrid2, tb, 0, stream>>>(cur_l, cur_r, row_start, cnt, csr_src, csr_ea,
                                           m_We + l * 128, m_att + l * 64, m_bias + l * 64,
                                           hbuf, N);
        if (l < ITER - 1) {
            k_projdual<<<pgrid, 256, 0, stream>>>(hbuf,
                                                  m_Wl + (size_t)(l + 1) * 4096, m_bl + (l + 1) * 64,
                                                  m_Wr + (size_t)(l + 1) * 4096, m_br + (l + 1) * 64,
                                                  alt_l, alt_r, N);
        } else {
            k_projpk<<<pgrid, 256, 0, stream>>>(hbuf,
                                                f_Wl, f_bl, s_Wl, s_bl,
                                                f_Wr, f_br, s_Wr, s_br,
                                                alt_l, N);
        }
        float* t;
        t = cur_l; cur_l = alt_l; alt_l = t;
        t = cur_r; cur_r = alt_r; alt_r = t;
    }
    k_gat_final<<<(N * 32 + tb - 1) / tb, tb, 0, stream>>>(cur_l, row_start, cnt, csr_src, csr_ea,
                                                           f_We, s_We, f_att, s_att,
                                                           f_bias, s_bias, fin, outv, N);
    k_sat_acc<<<(N + tb - 1) / tb, tb, 0, stream>>>(fin, mask, batch, sums, cnts, N);
    k_sat_fin<<<1, 64, 0, stream>>>(sums, cnts, outv + N, G);
}

// Round 7
// 612.089 us; speedup vs baseline: 1.1326x; 1.1326x over previous
//
#include <hip/hip_runtime.h>
#include <hip/hip_fp16.h>

// GATv2 stack on MI355X. fp32 throughout except the gathered xl payload.
// R22: fp16 xl-gather table. R15-R21 ledger: the edge/attention phase alone is
// ~45us/layer (R21 split attribution), invariant across 6 schedules, moving
// ~102MB of xl row-gathers through L2 with ~31MB L2-miss at an effective
// ~1.2 TB/s random-line fabric ceiling (fillBuffer hits 6.1 TB/s streaming on
// the same machine -> not HBM BW). Levers left: bytes/edge + L2 residency.
// xl stored fp16 (table 6.4MB->3.2MB: fits 4MB/XCD L2; gather lines/edge
// 4->2). xr, We/att/bias, logits, softmax, accumulation all fp32. Only the
// gathered payload is RNE-rounded -> absmax ~1e-3..1e-2 expected (first
// intentional numerics change; revert if the check fails).

static __device__ __forceinline__ float lrelu(float x, float s) {
    return fmaxf(x, s * x);  // exact for 0<s<1
}

// ---------------- degree + rank ----------------
__global__ void k_build0(const int* __restrict__ dst, int* __restrict__ cnt,
                         int* __restrict__ rank, int E) {
    int idx = blockIdx.x * blockDim.x + threadIdx.x;
    if (idx < E) rank[idx] = atomicAdd(&cnt[dst[idx]], 1);
}

// wave-aggregated segment offset allocation (exactly cnt[i] slots per node)
__global__ void k_segoff(const int* __restrict__ cnt, int* __restrict__ row_start,
                         int* __restrict__ cursor, int n) {
    int i = blockIdx.x * blockDim.x + threadIdx.x;
    int lane = threadIdx.x & 63;
    int v = (i < n) ? cnt[i] : 0;
    int s = v;
#pragma unroll
    for (int off = 1; off < 64; off <<= 1) {
        int t = __shfl_up(s, off);
        if (lane >= off) s += t;
    }
    int wavetot = __shfl(s, 63);
    int base = 0;
    if (lane == 63) base = atomicAdd(cursor, wavetot);
    base = __shfl(base, 63);
    if (i < n) row_start[i] = base + s - v;
}

__global__ void k_scatter(const int* __restrict__ src, const int* __restrict__ dst,
                          const float* __restrict__ ea, const int* __restrict__ rank,
                          const int* __restrict__ row_start,
                          int* __restrict__ csr_src, float* __restrict__ csr_ea, int E) {
    int e = blockIdx.x * blockDim.x + threadIdx.x;
    if (e >= E) return;
    int pos = row_start[dst[e]] + rank[e];
    csr_src[pos] = src[e];
    *(float2*)(csr_ea + 2 * (size_t)pos) = *(const float2*)(ea + 2 * (size_t)e);
}

// ---------------- layer-0 gat: on-the-fly rank-2 projection (fp32 exact) ----
__launch_bounds__(256, 8)
__global__ void k_gat0(const float* __restrict__ x,
                       const int* __restrict__ row_start, const int* __restrict__ cnt,
                       const int* __restrict__ csr_src, const float* __restrict__ csr_ea,
                       const float* __restrict__ Wl, const float* __restrict__ bl,
                       const float* __restrict__ Wr, const float* __restrict__ br,
                       const float* __restrict__ We, const float* __restrict__ att,
                       const float* __restrict__ bias,
                       float* __restrict__ out, int n) {
    int d = (blockIdx.x * blockDim.x + threadIdx.x) >> 6;
    int lane = threadIdx.x & 63;
    if (d >= n) return;
    const int p0 = __builtin_amdgcn_readfirstlane(row_start[d]);
    const int deg = __builtin_amdgcn_readfirstlane(cnt[d]);
    const int p1 = p0 + deg;
    const float wl0 = Wl[lane], wl1 = Wl[64 + lane], blv = bl[lane];
    const float we0 = We[lane], we1 = We[64 + lane];
    const float av = att[lane];
    const float2 xd = *(const float2*)(x + 2 * (size_t)d);
    const float xrv = fmaf(xd.x, Wr[lane], fmaf(xd.y, Wr[64 + lane], br[lane]));

    float den0 = 0.f, acc0 = 0.f;
    float den1 = 0.f, acc1 = 0.f;
    float s0 = 0.f, s1 = 0.f;

    auto step = [&](float xv, float2 ea, bool valid, float& den, float& acc) {
        float vm = valid ? 1.f : 0.f;
        s0 = fmaf(vm, ea.x, s0);
        s1 = fmaf(vm, ea.y, s1);
        float tv = lrelu(xv + xrv + ea.x * we0 + ea.y * we1, 0.2f) * av;
        tv += __shfl_xor(tv, 1);
        tv += __shfl_xor(tv, 2);
        if (!valid) tv = -__builtin_inff();
        float w = __expf(tv);
        den += w;
        acc += w * xv;
    };

    for (int p = p0; p < p1; p += 4) {
        int q1 = min(p + 1, p1 - 1), q2 = min(p + 2, p1 - 1), q3 = min(p + 3, p1 - 1);
        int e0s = csr_src[p], e1s = csr_src[q1], e2s = csr_src[q2], e3s = csr_src[q3];
        float2 ea0 = *(const float2*)(csr_ea + 2 * (size_t)p);
        float2 ea1 = *(const float2*)(csr_ea + 2 * (size_t)q1);
        float2 ea2 = *(const float2*)(csr_ea + 2 * (size_t)q2);
        float2 ea3 = *(const float2*)(csr_ea + 2 * (size_t)q3);
        float2 xs0 = *(const float2*)(x + 2 * (size_t)e0s);
        float2 xs1 = *(const float2*)(x + 2 * (size_t)e1s);
        float2 xs2 = *(const float2*)(x + 2 * (size_t)e2s);
        float2 xs3 = *(const float2*)(x + 2 * (size_t)e3s);
        float xv0 = fmaf(xs0.x, wl0, fmaf(xs0.y, wl1, blv));
        float xv1 = fmaf(xs1.x, wl0, fmaf(xs1.y, wl1, blv));
        float xv2 = fmaf(xs2.x, wl0, fmaf(xs2.y, wl1, blv));
        float xv3 = fmaf(xs3.x, wl0, fmaf(xs3.y, wl1, blv));
        step(xv0, ea0, true, den0, acc0);
        step(xv1, ea1, p + 1 < p1, den1, acc1);
        step(xv2, ea2, p + 2 < p1, den0, acc0);
        step(xv3, ea3, p + 3 < p1, den1, acc1);
    }
    {
        float c = fmaxf((float)deg, 1.f);
        float se0 = s0 / c, se1 = s1 / c;
        float xv = fmaf(xd.x, wl0, fmaf(xd.y, wl1, blv));
        float tv = lrelu(xv + xrv + se0 * we0 + se1 * we1, 0.2f) * av;
        tv += __shfl_xor(tv, 1);
        tv += __shfl_xor(tv, 2);
        float w = __expf(tv);
        den0 += w;
        acc0 += w * xv;
    }
    out[((size_t)d << 6) + lane] = (acc0 + acc1) / (den0 + den1) + bias[lane];
}

// ---------------- layer-0 projection with fused BN (reads hbuf) ----------------
// xl output in fp16 (gather payload); xr output fp32.
__launch_bounds__(256)
__global__ void k_proj64(const float* __restrict__ h,
                         const float* __restrict__ Wl, const float* __restrict__ bl,
                         const float* __restrict__ Wr, const float* __restrict__ br,
                         const double* __restrict__ stats,
                         const float* __restrict__ bng, const float* __restrict__ bnb,
                         __half* __restrict__ xl, float* __restrict__ xr, int n) {
    __shared__ float wsl[4096], wsr[4096], bna[64], bnbb[64];
    int t = threadIdx.x;
    for (int i = t; i < 4096; i += 256) { wsl[i] = Wl[i]; wsr[i] = Wr[i]; }
    if (t < 64) {
        double mu = stats[t] / n;
        double var = stats[64 + t] / n - mu * mu;
        float rs = (float)(1.0 / sqrt(var + 1e-5));
        float a = rs * bng[t];
        bna[t] = a;
        bnbb[t] = bnb[t] - (float)mu * a;
    }
    __syncthreads();
    int rg = t >> 2, cg4 = (t & 3) << 4;
    int r0 = blockIdx.x * 128 + rg * 2;
    float accl[2][16], accr[2][16];
#pragma unroll
    for (int r = 0; r < 2; ++r)
#pragma unroll
        for (int j = 0; j < 16; ++j) { accl[r][j] = 0.f; accr[r][j] = 0.f; }
    for (int k0 = 0; k0 < 64; k0 += 4) {
        float hk[2][4];
#pragma unroll
        for (int r = 0; r < 2; ++r) {
            int gr = r0 + r;
            float4 v = (gr < n) ? *(const float4*)(h + (size_t)gr * 64 + k0)
                                : make_float4(0.f, 0.f, 0.f, 0.f);
            hk[r][0] = v.x; hk[r][1] = v.y; hk[r][2] = v.z; hk[r][3] = v.w;
#pragma unroll
            for (int kk = 0; kk < 4; ++kk)
                hk[r][kk] = lrelu(hk[r][kk] * bna[k0 + kk] + bnbb[k0 + kk], 0.01f);
        }
#pragma unroll
        for (int kk = 0; kk < 4; ++kk) {
            const float* wl = wsl + (k0 + kk) * 64 + cg4;
            const float* wr = wsr + (k0 + kk) * 64 + cg4;
#pragma unroll
            for (int r = 0; r < 2; ++r)
#pragma unroll
                for (int j = 0; j < 16; ++j) {
                    accl[r][j] += hk[r][kk] * wl[j];
                    accr[r][j] += hk[r][kk] * wr[j];
                }
        }
    }
#pragma unroll
    for (int r = 0; r < 2; ++r) {
        int gr = r0 + r;
        if (gr < n) {
            __half* ol = xl + (size_t)gr * 64 + cg4;
            float* orr = xr + (size_t)gr * 64 + cg4;
#pragma unroll
            for (int j = 0; j < 16; ++j) {
                ol[j] = __float2half_rn(accl[r][j] + bl[cg4 + j]);
                orr[j] = accr[r][j] + br[cg4 + j];
            }
        }
    }
}

// ---------------- gat node body: fp16 xl gathers ----------------
__device__ __forceinline__ float gat_node(const __half* __restrict__ xl,
                                          const float* __restrict__ xr,
                                          const int* __restrict__ row_start,
                                          const int* __restrict__ cnt,
                                          const int* __restrict__ csr_src,
                                          const float* __restrict__ csr_ea,
                                          const float* __restrict__ We,
                                          const float* __restrict__ att,
                                          const float* __restrict__ bias,
                                          int d, int lane, int relu) {
    const int p0 = __builtin_amdgcn_readfirstlane(row_start[d]);
    const int deg = __builtin_amdgcn_readfirstlane(cnt[d]);
    const int p1 = p0 + deg;
    const float we0 = We[lane], we1 = We[64 + lane];
    const float av = att[lane];
    const float xrv = xr[((size_t)d << 6) + lane];

    float den0 = 0.f, acc0 = 0.f;
    float den1 = 0.f, acc1 = 0.f;
    float s0 = 0.f, s1 = 0.f;  // masked ea sums for the self-loop attr

    auto step = [&](float xv, float2 ea, bool valid, float& den, float& acc) {
        float vm = valid ? 1.f : 0.f;
        s0 = fmaf(vm, ea.x, s0);
        s1 = fmaf(vm, ea.y, s1);
        float tv = lrelu(xv + xrv + ea.x * we0 + ea.y * we1, 0.2f) * av;
        tv += __shfl_xor(tv, 1);
        tv += __shfl_xor(tv, 2);
        if (!valid) tv = -__builtin_inff();
        float w = __expf(tv);
        den += w;
        acc += w * xv;
    };

    for (int p = p0; p < p1; p += 4) {
        int q1 = min(p + 1, p1 - 1), q2 = min(p + 2, p1 - 1), q3 = min(p + 3, p1 - 1);
        int e0s = csr_src[p], e1s = csr_src[q1], e2s = csr_src[q2], e3s = csr_src[q3];
        float2 e0 = *(const float2*)(csr_ea + 2 * (size_t)p);
        float2 e1 = *(const float2*)(csr_ea + 2 * (size_t)q1);
        float2 e2 = *(const float2*)(csr_ea + 2 * (size_t)q2);
        float2 e3 = *(const float2*)(csr_ea + 2 * (size_t)q3);
        float x0 = __half2float(xl[((size_t)e0s << 6) + lane]);
        float x1 = __half2float(xl[((size_t)e1s << 6) + lane]);
        float x2 = __half2float(xl[((size_t)e2s << 6) + lane]);
        float x3 = __half2float(xl[((size_t)e3s << 6) + lane]);
        step(x0, e0, true, den0, acc0);
        step(x1, e1, p + 1 < p1, den1, acc1);
        step(x2, e2, p + 2 < p1, den0, acc0);
        step(x3, e3, p + 3 < p1, den1, acc1);
    }
    // self-loop: attr = segment mean, xv = own features
    {
        float c = fmaxf((float)deg, 1.f);
        float se0 = s0 / c, se1 = s1 / c;
        float xv = __half2float(xl[((size_t)d << 6) + lane]);
        float tv = lrelu(xv + xrv + se0 * we0 + se1 * we1, 0.2f) * av;
        tv += __shfl_xor(tv, 1);
        tv += __shfl_xor(tv, 2);
        float w = __expf(tv);
        den0 += w;
        acc0 += w * xv;
    }
    float o = (acc0 + acc1) / (den0 + den1) + bias[lane];
    if (relu) o = lrelu(o, 0.01f);
    return o;
}

// gat + fused next-layer dual projection epilogue, TWO nodes per wave,
// ONE wave per block. xl_out fp16, xr_out fp32.
__launch_bounds__(64, 8)
__global__ void k_gat_proj2(const __half* __restrict__ xl, const float* __restrict__ xr,
                            const int* __restrict__ row_start, const int* __restrict__ cnt,
                            const int* __restrict__ csr_src, const float* __restrict__ csr_ea,
                            const float* __restrict__ We, const float* __restrict__ att,
                            const float* __restrict__ bias,
                            const float* __restrict__ Wnl, const float* __restrict__ bnl,
                            const float* __restrict__ Wnr, const float* __restrict__ bnr,
                            __half* __restrict__ xl_out, float* __restrict__ xr_out, int n) {
    int wave = blockIdx.x;
    int lane = threadIdx.x & 63;
    int d0 = wave * 2, d1 = d0 + 1;
    if (d0 >= n) return;
    float o0 = gat_node(xl, xr, row_start, cnt, csr_src, csr_ea, We, att, bias, d0, lane, 1);
    float o1 = (d1 < n)
                   ? gat_node(xl, xr, row_start, cnt, csr_src, csr_ea, We, att, bias, d1, lane, 1)
                   : 0.f;
    float al0a = 0.f, al0b = 0.f, ar0a = 0.f, ar0b = 0.f;
    float al1a = 0.f, al1b = 0.f, ar1a = 0.f, ar1b = 0.f;
#pragma unroll 4
    for (int k = 0; k < 64; k += 2) {
        float h0a = __shfl(o0, k), h0b = __shfl(o0, k + 1);
        float h1a = __shfl(o1, k), h1b = __shfl(o1, k + 1);
        float wl0 = Wnl[k * 64 + lane], wl1 = Wnl[(k + 1) * 64 + lane];
        float wr0 = Wnr[k * 64 + lane], wr1 = Wnr[(k + 1) * 64 + lane];
        al0a += h0a * wl0; al0b += h0b * wl1;
        ar0a += h0a * wr0; ar0b += h0b * wr1;
        al1a += h1a * wl0; al1b += h1b * wl1;
        ar1a += h1a * wr0; ar1b += h1b * wr1;
    }
    float bL = bnl[lane], bR = bnr[lane];
    xl_out[((size_t)d0 << 6) + lane] = __float2half_rn(al0a + al0b + bL);
    xr_out[((size_t)d0 << 6) + lane] = ar0a + ar0b + bR;
    if (d1 < n) {
        xl_out[((size_t)d1 << 6) + lane] = __float2half_rn(al1a + al1b + bL);
        xr_out[((size_t)d1 << 6) + lane] = ar1a + ar1b + bR;
    }
}

// gat + fused FINAL packed projection epilogue, TWO nodes per wave, 1 wave/block.
// packed[d] (fp32) = [f_xl(16) | s_xl(16) | f_xr(16) | s_xr(16)]
__launch_bounds__(64, 8)
__global__ void k_gat_projfin2(const __half* __restrict__ xl, const float* __restrict__ xr,
                               const int* __restrict__ row_start, const int* __restrict__ cnt,
                               const int* __restrict__ csr_src, const float* __restrict__ csr_ea,
                               const float* __restrict__ We, const float* __restrict__ att,
                               const float* __restrict__ bias,
                               const float* __restrict__ fWl, const float* __restrict__ fbl,
                               const float* __restrict__ fWr, const float* __restrict__ fbr,
                               const float* __restrict__ sWl, const float* __restrict__ sbl,
                               const float* __restrict__ sWr, const float* __restrict__ sbr,
                               float* __restrict__ packed, int n) {
    int wave = blockIdx.x;
    int lane = threadIdx.x & 63;
    int d0 = wave * 2, d1 = d0 + 1;
    if (d0 >= n) return;
    float o0 = gat_node(xl, xr, row_start, cnt, csr_src, csr_ea, We, att, bias, d0, lane, 1);
    float o1 = (d1 < n)
                   ? gat_node(xl, xr, row_start, cnt, csr_src, csr_ea, We, att, bias, d1, lane, 1)
                   : 0.f;
    int q = lane >> 4, cc = lane & 15;
    const float* W = (q == 0) ? fWl : (q == 1) ? sWl : (q == 2) ? fWr : sWr;
    const float* B = (q == 0) ? fbl : (q == 1) ? sbl : (q == 2) ? fbr : sbr;
    float a0 = 0.f, a1 = 0.f, b0 = 0.f, b1 = 0.f;
#pragma unroll 4
    for (int k = 0; k < 64; k += 2) {
        float w0 = W[k * 16 + cc], w1 = W[(k + 1) * 16 + cc];
        a0 += __shfl(o0, k) * w0;
        a1 += __shfl(o0, k + 1) * w1;
        b0 += __shfl(o1, k) * w0;
        b1 += __shfl(o1, k + 1) * w1;
    }
    float bb = B[cc];
    packed[((size_t)d0 << 6) + lane] = a0 + a1 + bb;
    if (d1 < n) packed[((size_t)d1 << 6) + lane] = b0 + b1 + bb;
}

// final two H=16,C=1 layers fused: half-wave per dst (0-15 f -> fin, 16-31 s -> mus)
__launch_bounds__(256)
__global__ void k_gat_final(const float* __restrict__ packed,
                            const int* __restrict__ row_start, const int* __restrict__ cnt,
                            const int* __restrict__ csr_src, const float* __restrict__ csr_ea,
                            const float* __restrict__ fWe, const float* __restrict__ sWe,
                            const float* __restrict__ fatt, const float* __restrict__ satt,
                            const float* __restrict__ fbias, const float* __restrict__ sbias,
                            float* __restrict__ fin, float* __restrict__ mus, int n) {
    int hw = (blockIdx.x * blockDim.x + threadIdx.x) >> 5;
    if (hw >= n) return;
    int l = threadIdx.x & 31;
    int hh = l & 15, sel = l >> 4;
    const int d = hw;
    const int p0 = row_start[d], deg = cnt[d], p1 = p0 + deg;
    const float* We = sel ? sWe : fWe;
    float we0 = We[hh], we1 = We[16 + hh];
    float av = (sel ? satt : fatt)[hh];
    float xrv = packed[(size_t)d * 64 + 32 + sel * 16 + hh];
    int xli = sel * 16 + hh;

    float den0 = 0.f, acc0 = 0.f;
    float den1 = 0.f, acc1 = 0.f;
    float s0 = 0.f, s1 = 0.f;

    auto step = [&](float xv, float2 ea, bool valid, float& den, float& acc) {
        float vm = valid ? 1.f : 0.f;
        s0 = fmaf(vm, ea.x, s0);
        s1 = fmaf(vm, ea.y, s1);
        float t = lrelu(xv + xrv + ea.x * we0 + ea.y * we1, 0.2f) * av;
        if (!valid) t = -__builtin_inff();
        float w = __expf(t);
        den += w;
        acc += w * xv;
    };

    for (int p = p0; p < p1; p += 4) {
        int q1 = min(p + 1, p1 - 1), q2 = min(p + 2, p1 - 1), q3 = min(p + 3, p1 - 1);
        int e0s = csr_src[p], e1s = csr_src[q1], e2s = csr_src[q2], e3s = csr_src[q3];
        float2 e0 = *(const float2*)(csr_ea + 2 * (size_t)p);
        float2 e1 = *(const float2*)(csr_ea + 2 * (size_t)q1);
        float2 e2 = *(const float2*)(csr_ea + 2 * (size_t)q2);
        float2 e3 = *(const float2*)(csr_ea + 2 * (size_t)q3);
        float x0 = packed[(size_t)e0s * 64 + xli];
        float x1 = packed[(size_t)e1s * 64 + xli];
        float x2 = packed[(size_t)e2s * 64 + xli];
        float x3 = packed[(size_t)e3s * 64 + xli];
        step(x0, e0, true, den0, acc0);
        step(x1, e1, p + 1 < p1, den1, acc1);
        step(x2, e2, p + 2 < p1, den0, acc0);
        step(x3, e3, p + 3 < p1, den1, acc1);
    }
    {
        float c = fmaxf((float)deg, 1.f);
        float se0 = s0 / c, se1 = s1 / c;
        float xv = packed[(size_t)d * 64 + xli];
        float t = lrelu(xv + xrv + se0 * we0 + se1 * we1, 0.2f) * av;
        float w = __expf(t);
        den0 += w;
        acc0 += w * xv;
    }
    float val = (acc0 + acc1) / (den0 + den1);
#pragma unroll
    for (int w = 1; w < 16; w <<= 1) val += __shfl_xor(val, w);
    if ((threadIdx.x & 15) == 0) {
        float o = val * (1.f / 16.f) + (sel ? sbias[0] : fbias[0]);
        if (sel) mus[d] = o; else fin[d] = o;
    }
}

// ---------------- batchnorm stats ----------------

__global__ void k_bnstats(const float* __restrict__ h, double* __restrict__ stats, int n) {
    int c = threadIdx.x & 63;
    int s0 = blockIdx.x * (blockDim.x >> 6) + (threadIdx.x >> 6);
    int ns = gridDim.x * (blockDim.x >> 6);
    double s = 0.0, s2 = 0.0;
    for (int i = s0; i < n; i += ns) {
        float v = h[(size_t)i * 64 + c];
        s += v;
        s2 += (double)v * v;
    }
    atomicAdd(&stats[c], s);
    atomicAdd(&stats[64 + c], s2);
}

// ---------------- graph-level mean over masked nodes ----------------

__global__ void k_sat_acc(const float* __restrict__ fin, const int* __restrict__ mask,
                          const int* __restrict__ batch,
                          float* __restrict__ sums, float* __restrict__ cnts, int n) {
    int i = blockIdx.x * blockDim.x + threadIdx.x;
    int lane = threadIdx.x & 63;
    int g = (i < n) ? batch[i] : -1;
    float c = (i < n && mask[i] == 0) ? 1.f : 0.f;
    float v = (c > 0.f) ? fin[i] : 0.f;
#pragma unroll
    for (int off = 1; off < 64; off <<= 1) {
        float v2 = __shfl_down(v, off);
        float c2 = __shfl_down(c, off);
        int g2 = __shfl_down(g, off);
        if (lane + off < 64 && g2 == g) { v += v2; c += c2; }
    }
    int gprev = __shfl_up(g, 1);
    bool head = (lane == 0) || (gprev != g);
    if (head && g >= 0 && c > 0.f) {
        atomicAdd(&sums[g], v);
        atomicAdd(&cnts[g], c);
    }
}

__global__ void k_sat_fin(const float* __restrict__ sums, const float* __restrict__ cnts,
                          float* __restrict__ out, int g) {
    int i = threadIdx.x;
    if (i < g) out[i] = sums[i] / fmaxf(cnts[i], 1.f);
}

// ---------------- host ----------------

extern "C" void kernel_launch(void* const* d_in, const int* in_sizes, int n_in,
                              void* d_out, int out_size, void* d_ws, size_t ws_size,
                              hipStream_t stream) {
    const float* x = (const float*)d_in[0];
    const float* eat = (const float*)d_in[1];
    const int* ei = (const int*)d_in[2];
    const int* mask = (const int*)d_in[3];
    const int* batch = (const int*)d_in[4];
    const float* g0_Wl = (const float*)d_in[5];
    const float* g0_bl = (const float*)d_in[6];
    const float* g0_Wr = (const float*)d_in[7];
    const float* g0_br = (const float*)d_in[8];
    const float* g0_We = (const float*)d_in[9];
    const float* g0_att = (const float*)d_in[10];
    const float* g0_bias = (const float*)d_in[11];
    const float* bn_g = (const float*)d_in[12];
    const float* bn_b = (const float*)d_in[13];
    const float* m_Wl = (const float*)d_in[14];
    const float* m_bl = (const float*)d_in[15];
    const float* m_Wr = (const float*)d_in[16];
    const float* m_br = (const float*)d_in[17];
    const float* m_We = (const float*)d_in[18];
    const float* m_att = (const float*)d_in[19];
    const float* m_bias = (const float*)d_in[20];
    const float* f_Wl = (const float*)d_in[21];
    const float* f_bl = (const float*)d_in[22];
    const float* f_Wr = (const float*)d_in[23];
    const float* f_br = (const float*)d_in[24];
    const float* f_We = (const float*)d_in[25];
    const float* f_att = (const float*)d_in[26];
    const float* f_bias = (const float*)d_in[27];
    const float* s_Wl = (const float*)d_in[28];
    const float* s_bl = (const float*)d_in[29];
    const float* s_Wr = (const float*)d_in[30];
    const float* s_br = (const float*)d_in[31];
    const float* s_We = (const float*)d_in[32];
    const float* s_att = (const float*)d_in[33];
    const float* s_bias = (const float*)d_in[34];

    const int N = in_sizes[3];
    const int E = in_sizes[1] / 2;
    const int G = out_size - N;
    const int ITER = in_sizes[14] / 4096;
    const int* srcp = ei;
    const int* dstp = ei + E;

    char* wsb = (char*)d_ws;
    size_t off = 0;
    auto alloc = [&](size_t b) { void* p = wsb + off; off = (off + b + 255) & ~(size_t)255; return p; };
    int* cnt = (int*)alloc((size_t)N * 4);
    int* cursor = (int*)alloc(256);
    double* stats = (double*)alloc(128 * 8);
    float* sums = (float*)alloc((size_t)G * 4);
    float* cnts = (float*)alloc((size_t)G * 4);
    size_t zero_bytes = off;
    int* rank = (int*)alloc((size_t)E * 4);
    int* row_start = (int*)alloc((size_t)N * 4);
    int* csr_src = (int*)alloc((size_t)(E + 4) * 4);
    float* csr_ea = (float*)alloc((size_t)(E + 4) * 8);
    __half* xlA = (__half*)alloc((size_t)N * 128);
    float* xrA = (float*)alloc((size_t)N * 256);
    __half* xlB = (__half*)alloc((size_t)N * 128);
    float* xrB = (float*)alloc((size_t)N * 256);
    float* hbuf = (float*)alloc((size_t)N * 256);
    float* packed = (float*)alloc((size_t)N * 256);
    float* fin = (float*)alloc((size_t)N * 4);
    (void)ws_size; (void)n_in;

    float* outv = (float*)d_out;  // [0,N) = mus, [N,N+G) = sat

    hipMemsetAsync(d_ws, 0, zero_bytes, stream);
    const int tb = 256;
    const int ggrid = (N * 64 + 255) / 256;
    const int npair = (N + 1) / 2;
    k_build0<<<(E + tb - 1) / tb, tb, 0, stream>>>(dstp, cnt, rank, E);
    k_segoff<<<(N + tb - 1) / tb, tb, 0, stream>>>(cnt, row_start, cursor, N);
    k_scatter<<<(E + tb - 1) / tb, tb, 0, stream>>>(srcp, dstp, eat, rank, row_start,
                                                    csr_src, csr_ea, E);

    k_gat0<<<ggrid, tb, 0, stream>>>(x, row_start, cnt, csr_src, csr_ea,
                                     g0_Wl, g0_bl, g0_Wr, g0_br,
                                     g0_We, g0_att, g0_bias, hbuf, N);
    k_bnstats<<<128, 256, 0, stream>>>(hbuf, stats, N);
    k_proj64<<<(N + 127) / 128, 256, 0, stream>>>(hbuf, m_Wl, m_bl, m_Wr, m_br,
                                                  stats, bn_g, bn_b, xlA, xrA, N);

    __half* cur_l = xlA; float* cur_r = xrA;
    __half* alt_l = xlB; float* alt_r = xrB;
    for (int l = 0; l < ITER; ++l) {
        if (l < ITER - 1) {
            k_gat_proj2<<<npair, 64, 0, stream>>>(cur_l, cur_r, row_start, cnt, csr_src, csr_ea,
                                                  m_We + l * 128, m_att + l * 64, m_bias + l * 64,
                                                  m_Wl + (size_t)(l + 1) * 4096, m_bl + (l + 1) * 64,
                                                  m_Wr + (size_t)(l + 1) * 4096, m_br + (l + 1) * 64,
                                                  alt_l, alt_r, N);
        } else {
            k_gat_projfin2<<<npair, 64, 0, stream>>>(cur_l, cur_r, row_start, cnt, csr_src, csr_ea,
                                                     m_We + l * 128, m_att + l * 64, m_bias + l * 64,
                                                     f_Wl, f_bl, f_Wr, f_br,
                                                     s_Wl, s_bl, s_Wr, s_br,
                                                     packed, N);
        }
        __half* t = cur_l; cur_l = alt_l; alt_l = t;
        float* u = cur_r; cur_r = alt_r; alt_r = u;
    }
    k_gat_final<<<(N * 32 + tb - 1) / tb, tb, 0, stream>>>(packed, row_start, cnt, csr_src, csr_ea,
                                                           f_We, s_We, f_att, s_att,
                                                           f_bias, s_bias, fin, outv, N);
    k_sat_acc<<<(N + tb - 1) / tb, tb, 0, stream>>>(fin, mask, batch, sums, cnts, N);
    k_sat_fin<<<1, 64, 0, stream>>>(sums, cnts, outv + N, G);
}